// Round 17
// baseline (274.782 us; speedup 1.0000x reference)
//
#include <hip/hip_runtime.h>

namespace {

typedef __attribute__((ext_vector_type(8))) short short8;   // MFMA A/B frag (8 bf16)
typedef __attribute__((ext_vector_type(4))) float floatx4;  // MFMA C/D frag

constexpr int T    = 512;
constexpr int H    = 64;
constexpr int TPB  = 512;   // 8 waves = 2/SIMD (R12/R16 topology: bracketed optimum)
constexpr int MB   = 8;     // grid 256 -> 1 block/CU, all CUs
constexpr int HST  = 128;   // ushorts per bat row, EXACT (rotation-swizzled, no pad)
constexpr int XSTR = 516;   // xs row stride (floats)
constexpr int FSTR = 68;    // hf32 row stride (floats, head only)

constexpr int DPP_ROR8 = 0x128;  // row_ror:8 -> lane i reads lane i^8 (within row of 16)

__device__ __forceinline__ ushort f2bf(float x) {  // fp32 -> bf16 RN-even (finite)
  unsigned u = __float_as_uint(x);
  unsigned r = u + 0x7fffu + ((u >> 16) & 1u);
  return (ushort)(r >> 16);
}
__device__ __forceinline__ float bf2f(ushort h) {
  return __uint_as_float(((unsigned)h) << 16);
}
__device__ __forceinline__ float fsig(float x) {
  return __builtin_amdgcn_rcpf(1.0f + __expf(-x));
}
__device__ __forceinline__ float ftanh(float x) {
  return fmaf(-2.0f, __builtin_amdgcn_rcpf(1.0f + __expf(2.0f * x)), 1.0f);
}
__device__ __forceinline__ float swz8(float v) {   // value from lane^8 (row of 16), VALU pipe
  return __int_as_float(__builtin_amdgcn_update_dpp(
      0, __float_as_int(v), DPP_ROR8, 0xf, 0xf, true));
}

// R17 = R16 (240 us, verified) + rotation-swizzled h layout.
//   R16 counter-evidence: conflicts ROSE to 16.8M (128 cyc/step/CU) — the
//   {36*nhi+4*kg} dword offsets collide mod 32 at different addresses.
//   Fix: logical h_ext row (128 ushorts: hi[0,64) lo[64,128)) stored rotated
//   by 16*bat ushorts mod 128:  phys(bat, L) = 128*bat + ((L + 16*bat) & 127).
//   Read f0 (L = 64*nhi + 8*kg): dword quad = (kg + 2*bat) mod 8 -> exactly
//   8 lanes/quad = 2 lanes/bank = FREE (m136). Same for f1, writes ~2-way.
//   f1/write offsets precomputed separately (rotation wrap != +32).
// Everything else identical to R16: 8 waves x 2 tiles, fused 4-deep MFMA
// chain per tile (4-term split), gate-interleaved A-rows (verified R12),
// symmetric swz8 merge (verified R9/R12), 1 barrier/step, h double-buffered.
__global__ __launch_bounds__(TPB, 2)
void lstm_mfma(const float* __restrict__ xg,
               const float* __restrict__ W_ih,
               const float* __restrict__ W_hh,
               const float* __restrict__ b_ih,
               const float* __restrict__ b_hh,
               const float* __restrict__ fc1_w,
               const float* __restrict__ fc1_b,
               const float* __restrict__ fc2_w,
               const float* __restrict__ fc2_b,
               float* __restrict__ out)
{
  __shared__ __align__(16) ushort hA[MB * HST];   // h double-buffer (rot-swizzled rows)
  __shared__ __align__(16) ushort hB[MB * HST];
  __shared__ __align__(16) float  xs[MB * XSTR];
  __shared__ __align__(16) float  hf[MB * FSTR];  // final h fp32 (head; written once)
  __shared__ float zs[MB][16];

  const int tid  = threadIdx.x;
  const int b0   = blockIdx.x * MB;
  const int lane = tid & 63;
  const int wj   = tid >> 6;       // wave 0..7 -> tiles {2wj, 2wj+1}
  const int n    = lane & 15;      // MFMA col: batch n&7, type n>>3 (0=hi,1=lo)
  const int kg   = lane >> 4;      // k-group (A/B), row-quad (D)
  const int bat  = n & 7;
  const int nhi  = n >> 3;
  const int rot  = 16 * bat;       // per-bat rotation (ushorts)

  // ---- stage x (coalesced float4) ----
  for (int i = tid; i < MB * T / 4; i += TPB) {
    const int xb = i >> 7, tq = i & 127;
    float4 v = ((const float4*)(xg + (size_t)(b0 + xb) * T))[tq];
    *(float4*)&xs[xb * XSTR + tq * 4] = v;
  }
  // ---- zero h buffers (h0 = 0) ----
  for (int i = tid; i < MB * HST; i += TPB) { hA[i] = 0; hB[i] = 0; }

  // ---- A-frags for tiles 2wj, 2wj+1 (gate-interleaved permutation, verified R12) ----
  short8 whi[2][2], wlo[2][2];     // [tile][k-half]
#pragma unroll
  for (int tt = 0; tt < 2; ++tt) {
    const int r    = 2 * wj + tt;
    const int arow = 64 * (n & 3) + 4 * r + (n >> 2);   // gate n&3, local unit n>>2
    const float* wr = W_hh + arow * H + 8 * kg;
    const float4 p0 = *(const float4*)(wr + 0);
    const float4 p1 = *(const float4*)(wr + 4);
    const float4 p2 = *(const float4*)(wr + 32);
    const float4 p3 = *(const float4*)(wr + 36);
    const float v0[8] = {p0.x, p0.y, p0.z, p0.w, p1.x, p1.y, p1.z, p1.w};
    const float v1[8] = {p2.x, p2.y, p2.z, p2.w, p3.x, p3.y, p3.z, p3.w};
#pragma unroll
    for (int j = 0; j < 8; ++j) {
      const ushort h0 = f2bf(v0[j]);
      whi[tt][0][j] = (short)h0;
      wlo[tt][0][j] = (short)f2bf(v0[j] - bf2f(h0));   // exact remainder, then RN
      const ushort h1 = f2bf(v1[j]);
      whi[tt][1][j] = (short)h1;
      wlo[tt][1][j] = (short)f2bf(v1[j] - bf2f(h1));
    }
  }

  // ---- owned c-state: unit u = 8wj + 4nhi + kg, batch bat ----
  const int u = 8 * wj + 4 * nhi + kg;
  float bia[4], wih[4];
#pragma unroll
  for (int j = 0; j < 4; ++j) {                 // gate rows: i,f,g,o = 64j + u
    const int row = 64 * j + u;
    bia[j] = b_ih[row] + b_hh[row];
    wih[j] = W_ih[row];
  }

  // ---- swizzled LDS offsets (precomputed; rotation wrap => separate mods) ----
  const int Lrd   = 64 * nhi + 8 * kg;                      // logical read base
  const int rd0   = bat * HST + ((Lrd      + rot) & 127);   // f0 (k 0..31 of my type)
  const int rd1   = bat * HST + ((Lrd + 32 + rot) & 127);   // f1 (k 32..63)
  const int whi_o = bat * HST + ((u        + rot) & 127);   // h hi write
  const int wlo_o = bat * HST + ((u + 64   + rot) & 127);   // h lo write
  const float* xq = &xs[bat * XSTR];
  float c = 0.0f, hk = 0.0f;

  __syncthreads();

#define STEP(HR, HW, TT)                                                       \
  {                                                                            \
    const short8 f0 = *(const short8*)((HR) + rd0);                            \
    const short8 f1 = *(const short8*)((HR) + rd1);                            \
    const floatx4 zf = {0.f, 0.f, 0.f, 0.f};                                   \
    /* one fused 4-deep chain per tile (all 4 split terms C-accumulated) */    \
    floatx4 d = __builtin_amdgcn_mfma_f32_16x16x32_bf16(whi[0][0], f0, zf, 0, 0, 0); \
    floatx4 e = __builtin_amdgcn_mfma_f32_16x16x32_bf16(whi[1][0], f0, zf, 0, 0, 0); \
    d = __builtin_amdgcn_mfma_f32_16x16x32_bf16(wlo[0][0], f0, d, 0, 0, 0);    \
    e = __builtin_amdgcn_mfma_f32_16x16x32_bf16(wlo[1][0], f0, e, 0, 0, 0);    \
    d = __builtin_amdgcn_mfma_f32_16x16x32_bf16(whi[0][1], f1, d, 0, 0, 0);    \
    e = __builtin_amdgcn_mfma_f32_16x16x32_bf16(whi[1][1], f1, e, 0, 0, 0);    \
    d = __builtin_amdgcn_mfma_f32_16x16x32_bf16(wlo[0][1], f1, d, 0, 0, 0);    \
    e = __builtin_amdgcn_mfma_f32_16x16x32_bf16(wlo[1][1], f1, e, 0, 0, 0);    \
    const float xt = xq[(TT)];                                                 \
    float p[4];                                                                \
    _Pragma("unroll") for (int j = 0; j < 4; ++j) {                            \
      const float pA = d[j] + swz8(d[j]);        /* tile 2wj:   hi+lo cols */  \
      const float pB = e[j] + swz8(e[j]);        /* tile 2wj+1: hi+lo cols */  \
      p[j] = (nhi ? pB : pA) + fmaf(xt, wih[j], bia[j]);                       \
    }                                                                          \
    const float ig = fsig(p[0]);                                               \
    const float fg = fsig(p[1]);                                               \
    const float gc = ftanh(p[2]);                                              \
    const float og = fsig(p[3]);                                               \
    c  = fmaf(fg, c, ig * gc);                                                 \
    hk = og * ftanh(c);                                                        \
    const ushort hib = (ushort)(__float_as_uint(hk) >> 16);  /* trunc split */ \
    (HW)[whi_o] = hib;                                                         \
    (HW)[wlo_o] = f2bf(hk - bf2f(hib));   /* remainder exact, RN to bf16 */    \
    __syncthreads();                                                           \
  }

  for (int t = 0; t < T; t += 2) {
    STEP(hA, hB, t);
    STEP(hB, hA, t + 1);
  }
#undef STEP

  // ---- final h (fp32, from registers) -> LDS once; then the head ----
  hf[bat * FSTR + u] = hk;
  __syncthreads();
  if (tid < MB * 16) {
    const int bq = tid >> 4, j2 = tid & 15;   // 8 batches x 16 hidden2
    float s = fc1_b[j2];
    const float* fw = fc1_w + j2 * H;
#pragma unroll
    for (int k = 0; k < H; ++k) s = fmaf(hf[bq * FSTR + k], fw[k], s);
    s = fmaxf(s, 0.0f);
    zs[bq][j2] = s * fc2_w[j2];
  }
  __syncthreads();
  if (tid < MB) {
    float s = fc2_b[0];
#pragma unroll
    for (int j = 0; j < 16; ++j) s += zs[tid][j];
    out[b0 + tid] = s;
  }
}

}  // namespace

extern "C" void kernel_launch(void* const* d_in, const int* in_sizes, int n_in,
                              void* d_out, int out_size, void* d_ws, size_t ws_size,
                              hipStream_t stream) {
  const float* xg    = (const float*)d_in[0];
  const float* W_ih  = (const float*)d_in[1];
  const float* W_hh  = (const float*)d_in[2];
  const float* b_ih  = (const float*)d_in[3];
  const float* b_hh  = (const float*)d_in[4];
  const float* fc1_w = (const float*)d_in[5];
  const float* fc1_b = (const float*)d_in[6];
  const float* fc2_w = (const float*)d_in[7];
  const float* fc2_b = (const float*)d_in[8];
  float* out = (float*)d_out;

  dim3 grid(2048 / MB);   // 256 blocks -> 1 per CU, 8 waves = 2/SIMD
  dim3 block(TPB);
  hipLaunchKernelGGL(lstm_mfma, grid, block, 0, stream,
                     xg, W_ih, W_hh, b_ih, b_hh, fc1_w, fc1_b, fc2_w, fc2_b, out);
}

// Round 18
// 267.961 us; speedup vs baseline: 1.0255x; 1.0255x over previous
//
#include <hip/hip_runtime.h>

namespace {

typedef __attribute__((ext_vector_type(8))) short short8;   // MFMA A/B frag (8 bf16)
typedef __attribute__((ext_vector_type(4))) float floatx4;  // MFMA C/D frag

constexpr int T    = 512;
constexpr int H    = 64;
constexpr int TPB  = 512;   // 8 waves = 2/SIMD (R12/R16 topology: bracketed optimum)
constexpr int MB   = 8;     // grid 256 -> 1 block/CU, all CUs
constexpr int HST  = 128;   // ushorts per bat row, EXACT (rotation-swizzled, no pad)
constexpr int XSTR = 516;   // xs row stride (floats)
constexpr int FSTR = 68;    // hf32 row stride (floats, head only)

constexpr int DPP_ROR8 = 0x128;  // row_ror:8 -> lane i reads lane i^8 (within row of 16)

__device__ __forceinline__ ushort f2bf(float x) {  // fp32 -> bf16 RN-even (finite)
  unsigned u = __float_as_uint(x);
  unsigned r = u + 0x7fffu + ((u >> 16) & 1u);
  return (ushort)(r >> 16);
}
__device__ __forceinline__ float bf2f(ushort h) {
  return __uint_as_float(((unsigned)h) << 16);
}
__device__ __forceinline__ float fsig(float x) {
  return __builtin_amdgcn_rcpf(1.0f + __expf(-x));
}
__device__ __forceinline__ float ftanh(float x) {
  return fmaf(-2.0f, __builtin_amdgcn_rcpf(1.0f + __expf(2.0f * x)), 1.0f);
}
__device__ __forceinline__ float swz8(float v) {   // value from lane^8 (row of 16), VALU pipe
  return __int_as_float(__builtin_amdgcn_update_dpp(
      0, __float_as_int(v), DPP_ROR8, 0xf, 0xf, true));
}

// R18 = R17 (238 us) with the WRITE-bank fix + merge diet.
//   R17 evidence: conflicts 16.8M -> 12.6M (reads fixed) but writes still
//   ~4-way: rot=16*bat gives write bank term 8*bat mod 32 in {0,8,16,24}
//   (bats pair up). rot=24*bat: write bank = (4wj+2nhi+(kg>>1)+12*bat) mod 32,
//   12*bat mod 32 all-distinct; with the (2nhi+kg>>1) offsets the 64 lanes
//   cover all 32 banks exactly 2x (the dword-sharing kg-parity pair) -> free.
//   Reads: quad = (kg+3*bat+8nhi) mod 8 -> 8 lanes/quad = 2/bank -> free.
//   24*bat is a multiple of 8 ushorts -> b128 reads stay 16B-aligned.
//   Merge diet: select own/send (2 cndmask) BEFORE one DPP instead of two
//   DPP paths + select after (saves 4 VALU/lane/step). own = my tile's col
//   partial; send = other tile's (partner lane^8 has opposite nhi, so its
//   "send" is exactly my tile evaluated at the partner col type).
// Everything else identical to R16/R17 (verified): 8 waves x 2 tiles, fused
// 4-deep MFMA chain/tile, gate-interleaved A-rows, 1 barrier/step, h dbuf.
__global__ __launch_bounds__(TPB, 2)
void lstm_mfma(const float* __restrict__ xg,
               const float* __restrict__ W_ih,
               const float* __restrict__ W_hh,
               const float* __restrict__ b_ih,
               const float* __restrict__ b_hh,
               const float* __restrict__ fc1_w,
               const float* __restrict__ fc1_b,
               const float* __restrict__ fc2_w,
               const float* __restrict__ fc2_b,
               float* __restrict__ out)
{
  __shared__ __align__(16) ushort hA[MB * HST];   // h double-buffer (rot-swizzled rows)
  __shared__ __align__(16) ushort hB[MB * HST];
  __shared__ __align__(16) float  xs[MB * XSTR];
  __shared__ __align__(16) float  hf[MB * FSTR];  // final h fp32 (head; written once)
  __shared__ float zs[MB][16];

  const int tid  = threadIdx.x;
  const int b0   = blockIdx.x * MB;
  const int lane = tid & 63;
  const int wj   = tid >> 6;       // wave 0..7 -> tiles {2wj, 2wj+1}
  const int n    = lane & 15;      // MFMA col: batch n&7, type n>>3 (0=hi,1=lo)
  const int kg   = lane >> 4;      // k-group (A/B), row-quad (D)
  const int bat  = n & 7;
  const int nhi  = n >> 3;
  const int rot  = 24 * bat;       // per-bat rotation (ushorts; mult of 8 -> 16B-aligned)

  // ---- stage x (coalesced float4) ----
  for (int i = tid; i < MB * T / 4; i += TPB) {
    const int xb = i >> 7, tq = i & 127;
    float4 v = ((const float4*)(xg + (size_t)(b0 + xb) * T))[tq];
    *(float4*)&xs[xb * XSTR + tq * 4] = v;
  }
  // ---- zero h buffers (h0 = 0) ----
  for (int i = tid; i < MB * HST; i += TPB) { hA[i] = 0; hB[i] = 0; }

  // ---- A-frags for tiles 2wj, 2wj+1 (gate-interleaved permutation, verified R12) ----
  short8 whi[2][2], wlo[2][2];     // [tile][k-half]
#pragma unroll
  for (int tt = 0; tt < 2; ++tt) {
    const int r    = 2 * wj + tt;
    const int arow = 64 * (n & 3) + 4 * r + (n >> 2);   // gate n&3, local unit n>>2
    const float* wr = W_hh + arow * H + 8 * kg;
    const float4 p0 = *(const float4*)(wr + 0);
    const float4 p1 = *(const float4*)(wr + 4);
    const float4 p2 = *(const float4*)(wr + 32);
    const float4 p3 = *(const float4*)(wr + 36);
    const float v0[8] = {p0.x, p0.y, p0.z, p0.w, p1.x, p1.y, p1.z, p1.w};
    const float v1[8] = {p2.x, p2.y, p2.z, p2.w, p3.x, p3.y, p3.z, p3.w};
#pragma unroll
    for (int j = 0; j < 8; ++j) {
      const ushort h0 = f2bf(v0[j]);
      whi[tt][0][j] = (short)h0;
      wlo[tt][0][j] = (short)f2bf(v0[j] - bf2f(h0));   // exact remainder, then RN
      const ushort h1 = f2bf(v1[j]);
      whi[tt][1][j] = (short)h1;
      wlo[tt][1][j] = (short)f2bf(v1[j] - bf2f(h1));
    }
  }

  // ---- owned c-state: unit u = 8wj + 4nhi + kg, batch bat ----
  const int u = 8 * wj + 4 * nhi + kg;
  float bia[4], wih[4];
#pragma unroll
  for (int j = 0; j < 4; ++j) {                 // gate rows: i,f,g,o = 64j + u
    const int row = 64 * j + u;
    bia[j] = b_ih[row] + b_hh[row];
    wih[j] = W_ih[row];
  }

  // ---- swizzled LDS offsets (precomputed; rotation wrap => separate mods) ----
  const int Lrd   = 64 * nhi + 8 * kg;                      // logical read base
  const int rd0   = bat * HST + ((Lrd      + rot) & 127);   // f0 (k 0..31 of my type)
  const int rd1   = bat * HST + ((Lrd + 32 + rot) & 127);   // f1 (k 32..63)
  const int whi_o = bat * HST + ((u        + rot) & 127);   // h hi write
  const int wlo_o = bat * HST + ((u + 64   + rot) & 127);   // h lo write
  const float* xq = &xs[bat * XSTR];
  float c = 0.0f, hk = 0.0f;

  __syncthreads();

#define STEP(HR, HW, TT)                                                       \
  {                                                                            \
    const short8 f0 = *(const short8*)((HR) + rd0);                            \
    const short8 f1 = *(const short8*)((HR) + rd1);                            \
    const floatx4 zf = {0.f, 0.f, 0.f, 0.f};                                   \
    /* one fused 4-deep chain per tile (all 4 split terms C-accumulated) */    \
    floatx4 d = __builtin_amdgcn_mfma_f32_16x16x32_bf16(whi[0][0], f0, zf, 0, 0, 0); \
    floatx4 e = __builtin_amdgcn_mfma_f32_16x16x32_bf16(whi[1][0], f0, zf, 0, 0, 0); \
    d = __builtin_amdgcn_mfma_f32_16x16x32_bf16(wlo[0][0], f0, d, 0, 0, 0);    \
    e = __builtin_amdgcn_mfma_f32_16x16x32_bf16(wlo[1][0], f0, e, 0, 0, 0);    \
    d = __builtin_amdgcn_mfma_f32_16x16x32_bf16(whi[0][1], f1, d, 0, 0, 0);    \
    e = __builtin_amdgcn_mfma_f32_16x16x32_bf16(whi[1][1], f1, e, 0, 0, 0);    \
    d = __builtin_amdgcn_mfma_f32_16x16x32_bf16(wlo[0][1], f1, d, 0, 0, 0);    \
    e = __builtin_amdgcn_mfma_f32_16x16x32_bf16(wlo[1][1], f1, e, 0, 0, 0);    \
    const float xt = xq[(TT)];                                                 \
    float p[4];                                                                \
    _Pragma("unroll") for (int j = 0; j < 4; ++j) {                            \
      const float own  = nhi ? e[j] : d[j];   /* my tile @ my col type   */    \
      const float send = nhi ? d[j] : e[j];   /* partner's tile @ my col */    \
      p[j] = own + swz8(send) + fmaf(xt, wih[j], bia[j]);                      \
    }                                                                          \
    const float ig = fsig(p[0]);                                               \
    const float fg = fsig(p[1]);                                               \
    const float gc = ftanh(p[2]);                                              \
    const float og = fsig(p[3]);                                               \
    c  = fmaf(fg, c, ig * gc);                                                 \
    hk = og * ftanh(c);                                                        \
    const ushort hib = (ushort)(__float_as_uint(hk) >> 16);  /* trunc split */ \
    (HW)[whi_o] = hib;                                                         \
    (HW)[wlo_o] = f2bf(hk - bf2f(hib));   /* remainder exact, RN to bf16 */    \
    __syncthreads();                                                           \
  }

  for (int t = 0; t < T; t += 2) {
    STEP(hA, hB, t);
    STEP(hB, hA, t + 1);
  }
#undef STEP

  // ---- final h (fp32, from registers) -> LDS once; then the head ----
  hf[bat * FSTR + u] = hk;
  __syncthreads();
  if (tid < MB * 16) {
    const int bq = tid >> 4, j2 = tid & 15;   // 8 batches x 16 hidden2
    float s = fc1_b[j2];
    const float* fw = fc1_w + j2 * H;
#pragma unroll
    for (int k = 0; k < H; ++k) s = fmaf(hf[bq * FSTR + k], fw[k], s);
    s = fmaxf(s, 0.0f);
    zs[bq][j2] = s * fc2_w[j2];
  }
  __syncthreads();
  if (tid < MB) {
    float s = fc2_b[0];
#pragma unroll
    for (int j = 0; j < 16; ++j) s += zs[tid][j];
    out[b0 + tid] = s;
  }
}

}  // namespace

extern "C" void kernel_launch(void* const* d_in, const int* in_sizes, int n_in,
                              void* d_out, int out_size, void* d_ws, size_t ws_size,
                              hipStream_t stream) {
  const float* xg    = (const float*)d_in[0];
  const float* W_ih  = (const float*)d_in[1];
  const float* W_hh  = (const float*)d_in[2];
  const float* b_ih  = (const float*)d_in[3];
  const float* b_hh  = (const float*)d_in[4];
  const float* fc1_w = (const float*)d_in[5];
  const float* fc1_b = (const float*)d_in[6];
  const float* fc2_w = (const float*)d_in[7];
  const float* fc2_b = (const float*)d_in[8];
  float* out = (float*)d_out;

  dim3 grid(2048 / MB);   // 256 blocks -> 1 per CU, 8 waves = 2/SIMD
  dim3 block(TPB);
  hipLaunchKernelGGL(lstm_mfma, grid, block, 0, stream,
                     xg, W_ih, W_hh, b_ih, b_hh, fc1_w, fc1_b, fc2_w, fc2_b, out);
}

// Round 19
// 250.911 us; speedup vs baseline: 1.0951x; 1.0680x over previous
//
#include <hip/hip_runtime.h>

namespace {

typedef __attribute__((ext_vector_type(8))) short short8;   // MFMA A/B frag (8 bf16)
typedef __attribute__((ext_vector_type(4))) float floatx4;  // MFMA C/D frag

constexpr int T    = 512;
constexpr int H    = 64;
constexpr int TPB  = 512;   // 8 waves = 2/SIMD (R12/R16 topology: bracketed optimum)
constexpr int MB   = 8;     // grid 256 -> 1 block/CU, all CUs
constexpr int HST  = 128;   // ushorts per bat row, EXACT (rotation-swizzled, no pad)
constexpr int XSTR = 516;   // xs row stride (floats)
constexpr int FSTR = 68;    // hf32 row stride (floats, head only)

constexpr int DPP_ROR8 = 0x128;  // row_ror:8 -> lane i reads lane i^8 (within row of 16)

__device__ __forceinline__ ushort f2bf(float x) {  // fp32 -> bf16 RN-even (finite)
  unsigned u = __float_as_uint(x);
  unsigned r = u + 0x7fffu + ((u >> 16) & 1u);
  return (ushort)(r >> 16);
}
__device__ __forceinline__ float bf2f(ushort h) {
  return __uint_as_float(((unsigned)h) << 16);
}
__device__ __forceinline__ float fsig(float x) {
  return __builtin_amdgcn_rcpf(1.0f + __expf(-x));
}
__device__ __forceinline__ float ftanh(float x) {
  return fmaf(-2.0f, __builtin_amdgcn_rcpf(1.0f + __expf(2.0f * x)), 1.0f);
}
__device__ __forceinline__ float swz8(float v) {   // value from lane^8 (row of 16), VALU pipe
  return __int_as_float(__builtin_amdgcn_update_dpp(
      0, __float_as_int(v), DPP_ROR8, 0xf, 0xf, true));
}

// R19 = R18 (233 us, verified) + final micro-diet:
//   (1) float2 x-read: one ds_read_b64 per 2-step pair (t even -> 8B aligned).
//   (2) trunc split for BOTH halves: hi = trunc(hk), lo = trunc(hk - hi).
//       lo error grows 2^-17 -> 2^-16 of |h| (absmax ~6e-5, 15x under thresh);
//       saves the RN add/mask sequence (~3 VALU/lane/step).
// Structure (all verified): 8 waves x 2 tiles, fused 4-deep MFMA chain/tile
// (4-term bf16 split), gate-interleaved A-rows (R12), rot=24*bat swizzle
// (R18: reads 2-way free, writes 2-way), own/send cndmask + 1 DPP merge,
// 1 barrier/step, h double-buffered.
// Structural floor note: each lane's B-frag spans all 64 k -> every wave
// depends on all 8 waves' h-writes -> full barrier forced; topology space
// bracketed by R6/R10-R15 (dup or barrier taxes exceed decoupling gains).
__global__ __launch_bounds__(TPB, 2)
void lstm_mfma(const float* __restrict__ xg,
               const float* __restrict__ W_ih,
               const float* __restrict__ W_hh,
               const float* __restrict__ b_ih,
               const float* __restrict__ b_hh,
               const float* __restrict__ fc1_w,
               const float* __restrict__ fc1_b,
               const float* __restrict__ fc2_w,
               const float* __restrict__ fc2_b,
               float* __restrict__ out)
{
  __shared__ __align__(16) ushort hA[MB * HST];   // h double-buffer (rot-swizzled rows)
  __shared__ __align__(16) ushort hB[MB * HST];
  __shared__ __align__(16) float  xs[MB * XSTR];
  __shared__ __align__(16) float  hf[MB * FSTR];  // final h fp32 (head; written once)
  __shared__ float zs[MB][16];

  const int tid  = threadIdx.x;
  const int b0   = blockIdx.x * MB;
  const int lane = tid & 63;
  const int wj   = tid >> 6;       // wave 0..7 -> tiles {2wj, 2wj+1}
  const int n    = lane & 15;      // MFMA col: batch n&7, type n>>3 (0=hi,1=lo)
  const int kg   = lane >> 4;      // k-group (A/B), row-quad (D)
  const int bat  = n & 7;
  const int nhi  = n >> 3;
  const int rot  = 24 * bat;       // per-bat rotation (ushorts; mult of 8 -> 16B-aligned)

  // ---- stage x (coalesced float4) ----
  for (int i = tid; i < MB * T / 4; i += TPB) {
    const int xb = i >> 7, tq = i & 127;
    float4 v = ((const float4*)(xg + (size_t)(b0 + xb) * T))[tq];
    *(float4*)&xs[xb * XSTR + tq * 4] = v;
  }
  // ---- zero h buffers (h0 = 0) ----
  for (int i = tid; i < MB * HST; i += TPB) { hA[i] = 0; hB[i] = 0; }

  // ---- A-frags for tiles 2wj, 2wj+1 (gate-interleaved permutation, verified R12) ----
  short8 whi[2][2], wlo[2][2];     // [tile][k-half]
#pragma unroll
  for (int tt = 0; tt < 2; ++tt) {
    const int r    = 2 * wj + tt;
    const int arow = 64 * (n & 3) + 4 * r + (n >> 2);   // gate n&3, local unit n>>2
    const float* wr = W_hh + arow * H + 8 * kg;
    const float4 p0 = *(const float4*)(wr + 0);
    const float4 p1 = *(const float4*)(wr + 4);
    const float4 p2 = *(const float4*)(wr + 32);
    const float4 p3 = *(const float4*)(wr + 36);
    const float v0[8] = {p0.x, p0.y, p0.z, p0.w, p1.x, p1.y, p1.z, p1.w};
    const float v1[8] = {p2.x, p2.y, p2.z, p2.w, p3.x, p3.y, p3.z, p3.w};
#pragma unroll
    for (int j = 0; j < 8; ++j) {
      const ushort h0 = f2bf(v0[j]);
      whi[tt][0][j] = (short)h0;
      wlo[tt][0][j] = (short)f2bf(v0[j] - bf2f(h0));   // exact remainder, then RN
      const ushort h1 = f2bf(v1[j]);
      whi[tt][1][j] = (short)h1;
      wlo[tt][1][j] = (short)f2bf(v1[j] - bf2f(h1));
    }
  }

  // ---- owned c-state: unit u = 8wj + 4nhi + kg, batch bat ----
  const int u = 8 * wj + 4 * nhi + kg;
  float bia[4], wih[4];
#pragma unroll
  for (int j = 0; j < 4; ++j) {                 // gate rows: i,f,g,o = 64j + u
    const int row = 64 * j + u;
    bia[j] = b_ih[row] + b_hh[row];
    wih[j] = W_ih[row];
  }

  // ---- swizzled LDS offsets (precomputed; rotation wrap => separate mods) ----
  const int Lrd   = 64 * nhi + 8 * kg;                      // logical read base
  const int rd0   = bat * HST + ((Lrd      + rot) & 127);   // f0 (k 0..31 of my type)
  const int rd1   = bat * HST + ((Lrd + 32 + rot) & 127);   // f1 (k 32..63)
  const int whi_o = bat * HST + ((u        + rot) & 127);   // h hi write
  const int wlo_o = bat * HST + ((u + 64   + rot) & 127);   // h lo write
  const float* xq = &xs[bat * XSTR];
  float c = 0.0f, hk = 0.0f;

  __syncthreads();

#define STEP(HR, HW, XT)                                                       \
  {                                                                            \
    const short8 f0 = *(const short8*)((HR) + rd0);                            \
    const short8 f1 = *(const short8*)((HR) + rd1);                            \
    const floatx4 zf = {0.f, 0.f, 0.f, 0.f};                                   \
    /* one fused 4-deep chain per tile (all 4 split terms C-accumulated) */    \
    floatx4 d = __builtin_amdgcn_mfma_f32_16x16x32_bf16(whi[0][0], f0, zf, 0, 0, 0); \
    floatx4 e = __builtin_amdgcn_mfma_f32_16x16x32_bf16(whi[1][0], f0, zf, 0, 0, 0); \
    d = __builtin_amdgcn_mfma_f32_16x16x32_bf16(wlo[0][0], f0, d, 0, 0, 0);    \
    e = __builtin_amdgcn_mfma_f32_16x16x32_bf16(wlo[1][0], f0, e, 0, 0, 0);    \
    d = __builtin_amdgcn_mfma_f32_16x16x32_bf16(whi[0][1], f1, d, 0, 0, 0);    \
    e = __builtin_amdgcn_mfma_f32_16x16x32_bf16(whi[1][1], f1, e, 0, 0, 0);    \
    d = __builtin_amdgcn_mfma_f32_16x16x32_bf16(wlo[0][1], f1, d, 0, 0, 0);    \
    e = __builtin_amdgcn_mfma_f32_16x16x32_bf16(wlo[1][1], f1, e, 0, 0, 0);    \
    float p[4];                                                                \
    _Pragma("unroll") for (int j = 0; j < 4; ++j) {                            \
      const float own  = nhi ? e[j] : d[j];   /* my tile @ my col type   */    \
      const float send = nhi ? d[j] : e[j];   /* partner's tile @ my col */    \
      p[j] = own + swz8(send) + fmaf((XT), wih[j], bia[j]);                    \
    }                                                                          \
    const float ig = fsig(p[0]);                                               \
    const float fg = fsig(p[1]);                                               \
    const float gc = ftanh(p[2]);                                              \
    const float og = fsig(p[3]);                                               \
    c  = fmaf(fg, c, ig * gc);                                                 \
    hk = og * ftanh(c);                                                        \
    /* trunc split for both halves (R19): hi = trunc(hk), lo = trunc(hk-hi) */ \
    const ushort hib = (ushort)(__float_as_uint(hk) >> 16);                    \
    const float  rem = hk - bf2f(hib);                                         \
    (HW)[whi_o] = hib;                                                         \
    (HW)[wlo_o] = (ushort)(__float_as_uint(rem) >> 16);                        \
    __syncthreads();                                                           \
  }

  for (int t = 0; t < T; t += 2) {
    const float2 x2 = *(const float2*)(xq + t);   // one b64 read feeds both steps
    STEP(hA, hB, x2.x);
    STEP(hB, hA, x2.y);
  }
#undef STEP

  // ---- final h (fp32, from registers) -> LDS once; then the head ----
  hf[bat * FSTR + u] = hk;
  __syncthreads();
  if (tid < MB * 16) {
    const int bq = tid >> 4, j2 = tid & 15;   // 8 batches x 16 hidden2
    float s = fc1_b[j2];
    const float* fw = fc1_w + j2 * H;
#pragma unroll
    for (int k = 0; k < H; ++k) s = fmaf(hf[bq * FSTR + k], fw[k], s);
    s = fmaxf(s, 0.0f);
    zs[bq][j2] = s * fc2_w[j2];
  }
  __syncthreads();
  if (tid < MB) {
    float s = fc2_b[0];
#pragma unroll
    for (int j = 0; j < 16; ++j) s += zs[tid][j];
    out[b0 + tid] = s;
  }
}

}  // namespace

extern "C" void kernel_launch(void* const* d_in, const int* in_sizes, int n_in,
                              void* d_out, int out_size, void* d_ws, size_t ws_size,
                              hipStream_t stream) {
  const float* xg    = (const float*)d_in[0];
  const float* W_ih  = (const float*)d_in[1];
  const float* W_hh  = (const float*)d_in[2];
  const float* b_ih  = (const float*)d_in[3];
  const float* b_hh  = (const float*)d_in[4];
  const float* fc1_w = (const float*)d_in[5];
  const float* fc1_b = (const float*)d_in[6];
  const float* fc2_w = (const float*)d_in[7];
  const float* fc2_b = (const float*)d_in[8];
  float* out = (float*)d_out;

  dim3 grid(2048 / MB);   // 256 blocks -> 1 per CU, 8 waves = 2/SIMD
  dim3 block(TPB);
  hipLaunchKernelGGL(lstm_mfma, grid, block, 0, stream,
                     xg, W_ih, W_hh, b_ih, b_hh, fc1_w, fc1_b, fc2_w, fc2_b, out);
}